// Round 6
// baseline (2052.113 us; speedup 1.0000x reference)
//
#include <hip/hip_runtime.h>
#include <math.h>

#define NN   40000
#define EE   640000
#define HID  32
#define FEAT 16
#define LAB  4
#define TT   8
#define DIN  53   // FEAT + LAB + HID + 1
#define WD   (HID * DIN)

// ---------------- CSR build ----------------

__global__ __launch_bounds__(256) void zero_i32(int* __restrict__ p, int n) {
    int i = blockIdx.x * 256 + threadIdx.x;
    if (i < n) p[i] = 0;
}

__global__ __launch_bounds__(256) void hist_kernel(const int* __restrict__ dst,
                                                   int* __restrict__ deg) {
    int e = blockIdx.x * 256 + threadIdx.x;
    if (e < EE) atomicAdd(&deg[dst[e]], 1);
}

// single-block exclusive scan over deg -> row_ptr (N+1), wave-shuffle based
__global__ __launch_bounds__(1024) void scan_kernel(const int* __restrict__ deg,
                                                    int* __restrict__ row_ptr) {
    __shared__ int wsum[16];
    __shared__ int chunk_total;
    int tid = threadIdx.x;
    int lane = tid & 63, wv = tid >> 6;
    int carry = 0;
    if (tid == 0) row_ptr[0] = 0;
    for (int base = 0; base < NN; base += 1024) {
        int i = base + tid;
        int v = (i < NN) ? deg[i] : 0;
        #pragma unroll
        for (int o = 1; o < 64; o <<= 1) {
            int t = __shfl_up(v, o);
            if (lane >= o) v += t;
        }
        if (lane == 63) wsum[wv] = v;
        __syncthreads();
        if (tid < 16) {
            int s = wsum[tid];
            #pragma unroll
            for (int o = 1; o < 16; o <<= 1) {
                int t = __shfl_up(s, o);
                if (tid >= o) s += t;
            }
            wsum[tid] = s;
            if (tid == 15) chunk_total = s;
        }
        __syncthreads();
        int woff = (wv == 0) ? 0 : wsum[wv - 1];
        if (i < NN) row_ptr[i + 1] = carry + woff + v;
        carry += chunk_total;
        __syncthreads();
    }
}

__global__ __launch_bounds__(256) void scatter_kernel(const int* __restrict__ src,
                                                      const int* __restrict__ dst,
                                                      const int* __restrict__ row_ptr,
                                                      int* __restrict__ cursor,
                                                      int* __restrict__ csr_src) {
    int e = blockIdx.x * 256 + threadIdx.x;
    if (e < EE) {
        int d = dst[e];
        int pos = atomicAdd(&cursor[d], 1);
        csr_src[row_ptr[d] + pos] = src[e];
    }
}

// ---------------- state init ----------------

__global__ __launch_bounds__(256) void init_kernel(const float* __restrict__ x0,
                                                   const float* __restrict__ mask,
                                                   float* __restrict__ hidden,
                                                   float* __restrict__ x2) {
    int i = blockIdx.x * 256 + threadIdx.x;
    if (i < NN * HID) hidden[i] = 1.0f;
    if (i < NN * FEAT) {
        int node = i >> 4;
        x2[i] = (mask[node] > 0.5f) ? x0[i] : 0.0f;
    }
}

// ---------------- dense01: both sigmoid-gate projections in one pass -------
// inp = [feat16, mask, labels4, h32]; outputs interleaved [node][gate][32]

__global__ __launch_bounds__(256) void dense01_kernel(const float* __restrict__ feat,
                                                      const float* __restrict__ mask,
                                                      const float* __restrict__ labels,
                                                      const float* __restrict__ hsrc,
                                                      const float* __restrict__ Wl,
                                                      const float* __restrict__ bl,
                                                      const float* __restrict__ Wr,
                                                      const float* __restrict__ br,
                                                      float* __restrict__ xl01,
                                                      float* __restrict__ xr01) {
    __shared__ float W_s[4 * WD];     // Wl0 | Wl1 | Wr0 | Wr1
    __shared__ float inp_s[8][DIN];
    for (int idx = threadIdx.x; idx < WD; idx += 256) {
        W_s[idx]          = Wl[idx];
        W_s[WD + idx]     = Wl[WD + idx];
        W_s[2 * WD + idx] = Wr[idx];
        W_s[3 * WD + idx] = Wr[WD + idx];
    }
    int ni = threadIdx.x >> 5, k = threadIdx.x & 31;
    int node = blockIdx.x * 8 + ni;
    for (int i = k; i < DIN; i += 32) {
        float v;
        if (i < 16)       v = feat[node * 16 + i];
        else if (i == 16) v = mask[node];
        else if (i < 21)  v = labels[node * 4 + (i - 17)];
        else              v = hsrc[node * 32 + (i - 21)];
        inp_s[ni][i] = v;
    }
    __syncthreads();
    float l0 = bl[k], l1 = bl[HID + k], r0 = br[k], r1 = br[HID + k];
    const float* w0 = &W_s[k * DIN];
    const float* w1 = &W_s[WD + k * DIN];
    const float* w2 = &W_s[2 * WD + k * DIN];
    const float* w3 = &W_s[3 * WD + k * DIN];
#pragma unroll
    for (int i = 0; i < DIN; ++i) {
        float xv = inp_s[ni][i];
        l0 += xv * w0[i];
        l1 += xv * w1[i];
        r0 += xv * w2[i];
        r1 += xv * w3[i];
    }
    xl01[node * 64 + k]      = l0;
    xl01[node * 64 + 32 + k] = l1;
    xr01[node * 64 + k]      = r0;
    xr01[node * 64 + 32 + k] = r1;
}

// ---------------- dense: xl = inp@Wl.T+bl, xr = inp@Wr.T+br (one gate) -----
// inp = [feat16, mask, labels4, h32 * hmul]

__global__ __launch_bounds__(256) void dense_kernel(const float* __restrict__ feat,
                                                    const float* __restrict__ mask,
                                                    const float* __restrict__ labels,
                                                    const float* __restrict__ hsrc,
                                                    const float* __restrict__ hmul,
                                                    const float* __restrict__ Wl,
                                                    const float* __restrict__ bl,
                                                    const float* __restrict__ Wr,
                                                    const float* __restrict__ br,
                                                    float* __restrict__ xl,
                                                    float* __restrict__ xr) {
    __shared__ float Wl_s[WD];
    __shared__ float Wr_s[WD];
    __shared__ float inp_s[8][DIN];
    for (int idx = threadIdx.x; idx < WD; idx += 256) {
        Wl_s[idx] = Wl[idx];
        Wr_s[idx] = Wr[idx];
    }
    int ni = threadIdx.x >> 5, k = threadIdx.x & 31;
    int node = blockIdx.x * 8 + ni;
    for (int i = k; i < DIN; i += 32) {
        float v;
        if (i < 16)       v = feat[node * 16 + i];
        else if (i == 16) v = mask[node];
        else if (i < 21)  v = labels[node * 4 + (i - 17)];
        else              v = hsrc[node * 32 + (i - 21)] * hmul[node * 32 + (i - 21)];
        inp_s[ni][i] = v;
    }
    __syncthreads();
    float al = bl[k], ar = br[k];
    const float* wlr = &Wl_s[k * DIN];
    const float* wrr = &Wr_s[k * DIN];
#pragma unroll
    for (int i = 0; i < DIN; ++i) {
        float xv = inp_s[ni][i];
        al += xv * wlr[i];
        ar += xv * wrr[i];
    }
    xl[node * 32 + k] = al;
    xr[node * 32 + k] = ar;
}

// -------- shared conv helpers (one node per 64-lane wave) ------------------
// lane = g*4+j : group g strides edges by 16; lane slice j = channels [j*8,j*8+8)

__device__ __forceinline__ float edge_score(const float4& v0, const float4& v1,
                                            const float4& xr0, const float4& xr1,
                                            const float4& at0, const float4& at1) {
    float part, z;
    z = v0.x + xr0.x; z = (z > 0.f) ? z : 0.2f * z; part  = z * at0.x;
    z = v0.y + xr0.y; z = (z > 0.f) ? z : 0.2f * z; part += z * at0.y;
    z = v0.z + xr0.z; z = (z > 0.f) ? z : 0.2f * z; part += z * at0.z;
    z = v0.w + xr0.w; z = (z > 0.f) ? z : 0.2f * z; part += z * at0.w;
    z = v1.x + xr1.x; z = (z > 0.f) ? z : 0.2f * z; part += z * at1.x;
    z = v1.y + xr1.y; z = (z > 0.f) ? z : 0.2f * z; part += z * at1.y;
    z = v1.z + xr1.z; z = (z > 0.f) ? z : 0.2f * z; part += z * at1.z;
    z = v1.w + xr1.w; z = (z > 0.f) ? z : 0.2f * z; part += z * at1.w;
    part += __shfl_xor(part, 1);
    part += __shfl_xor(part, 2);
    return part;
}

__device__ __forceinline__ void online_update(float e, float& m, float& den, float* acc,
                                              const float4& v0, const float4& v1) {
    if (e > m) {
        float sc = __expf(m - e);
        den *= sc;
#pragma unroll
        for (int i = 0; i < 8; ++i) acc[i] *= sc;
        m = e;
    }
    float a = __expf(e - m);
    den += a;
    acc[0] += a * v0.x; acc[1] += a * v0.y; acc[2] += a * v0.z; acc[3] += a * v0.w;
    acc[4] += a * v1.x; acc[5] += a * v1.y; acc[6] += a * v1.z; acc[7] += a * v1.w;
}

// merge the 16 per-group online softmaxes; all lanes end with merged o[8]
__device__ __forceinline__ void merge_groups(float m, float den, const float* acc,
                                             bool nonempty, float* o) {
    if (nonempty) {
        float mt = m;
        mt = fmaxf(mt, __shfl_xor(mt, 4));
        mt = fmaxf(mt, __shfl_xor(mt, 8));
        mt = fmaxf(mt, __shfl_xor(mt, 16));
        mt = fmaxf(mt, __shfl_xor(mt, 32));
        float sc = __expf(m - mt);          // empty group: exp(-inf) = 0
        float d = den * sc;
        d += __shfl_xor(d, 4);
        d += __shfl_xor(d, 8);
        d += __shfl_xor(d, 16);
        d += __shfl_xor(d, 32);
#pragma unroll
        for (int i = 0; i < 8; ++i) {
            float t = acc[i] * sc;
            t += __shfl_xor(t, 4);
            t += __shfl_xor(t, 8);
            t += __shfl_xor(t, 16);
            t += __shfl_xor(t, 32);
            o[i] = t / d;                    // d >= 1 (max group contributes 1)
        }
    } else {
#pragma unroll
        for (int i = 0; i < 8; ++i) o[i] = 0.0f;
    }
}

// ---------------- conv01: both sigmoid gates in one CSR walk ---------------
// xl01/xr01 layout [node][gate][32]; 256B contiguous gather per edge.

__global__ __launch_bounds__(256) void conv01_kernel(const int* __restrict__ row_ptr,
                                                     const int* __restrict__ csr_src,
                                                     const float* __restrict__ xl01,
                                                     const float* __restrict__ xr01,
                                                     const float* __restrict__ att,
                                                     const float* __restrict__ bconv,
                                                     float* __restrict__ g0,
                                                     float* __restrict__ g1) {
    int wid  = threadIdx.x >> 6;
    int lane = threadIdx.x & 63;
    int g = lane >> 2, j = lane & 3;
    int n = blockIdx.x * 4 + wid;
    int c0 = j * 8;
    int beg = row_ptr[n], end = row_ptr[n + 1];

    float4 a00 = *(const float4*)(att + c0);
    float4 a01 = *(const float4*)(att + c0 + 4);
    float4 a10 = *(const float4*)(att + 32 + c0);
    float4 a11 = *(const float4*)(att + 32 + c0 + 4);
    const float* xrn = xr01 + n * 64;
    float4 xr00 = *(const float4*)(xrn + c0);
    float4 xr01v = *(const float4*)(xrn + c0 + 4);
    float4 xr10 = *(const float4*)(xrn + 32 + c0);
    float4 xr11 = *(const float4*)(xrn + 32 + c0 + 4);

    float m0 = -INFINITY, den0 = 0.0f, acc0[8] = {0, 0, 0, 0, 0, 0, 0, 0};
    float m1 = -INFINITY, den1 = 0.0f, acc1[8] = {0, 0, 0, 0, 0, 0, 0, 0};

    for (int p = beg + g; p < end; p += 16) {
        int s = csr_src[p];
        const float4* rp = (const float4*)(xl01 + s * 64 + c0);
        const float4* rq = (const float4*)(xl01 + s * 64 + 32 + c0);
        float4 v00 = rp[0], v01 = rp[1];
        float4 v10 = rq[0], v11 = rq[1];
        float e0 = edge_score(v00, v01, xr00, xr01v, a00, a01);
        float e1 = edge_score(v10, v11, xr10, xr11, a10, a11);
        online_update(e0, m0, den0, acc0, v00, v01);
        online_update(e1, m1, den1, acc1, v10, v11);
    }

    float o0[8], o1[8];
    bool ne = beg < end;
    merge_groups(m0, den0, acc0, ne, o0);
    merge_groups(m1, den1, acc1, ne, o1);

    if (g == 0) {
        float4 b00 = *(const float4*)(bconv + c0);
        float4 b01 = *(const float4*)(bconv + c0 + 4);
        float4 b10 = *(const float4*)(bconv + 32 + c0);
        float4 b11 = *(const float4*)(bconv + 32 + c0 + 4);
        float r0[8] = {o0[0] + b00.x, o0[1] + b00.y, o0[2] + b00.z, o0[3] + b00.w,
                       o0[4] + b01.x, o0[5] + b01.y, o0[6] + b01.z, o0[7] + b01.w};
        float r1[8] = {o1[0] + b10.x, o1[1] + b10.y, o1[2] + b10.z, o1[3] + b10.w,
                       o1[4] + b11.x, o1[5] + b11.y, o1[6] + b11.z, o1[7] + b11.w};
#pragma unroll
        for (int i = 0; i < 8; ++i) {
            r0[i] = 1.0f / (1.0f + __expf(-r0[i]));
            r1[i] = 1.0f / (1.0f + __expf(-r1[i]));
        }
        float4* p0 = (float4*)(g0 + n * 32 + c0);
        p0[0] = make_float4(r0[0], r0[1], r0[2], r0[3]);
        p0[1] = make_float4(r0[4], r0[5], r0[6], r0[7]);
        float4* p1 = (float4*)(g1 + n * 32 + c0);
        p1[0] = make_float4(r1[0], r1[1], r1[2], r1[3]);
        p1[1] = make_float4(r1[4], r1[5], r1[6], r1[7]);
    }
}

// ---------------- conv (single gate, tanh) for the cell gate ---------------

__global__ __launch_bounds__(256) void conv2_kernel(const int* __restrict__ row_ptr,
                                                    const int* __restrict__ csr_src,
                                                    const float* __restrict__ xl,
                                                    const float* __restrict__ xr,
                                                    const float* __restrict__ att,
                                                    const float* __restrict__ bconv,
                                                    float* __restrict__ out) {
    int wid  = threadIdx.x >> 6;
    int lane = threadIdx.x & 63;
    int g = lane >> 2, j = lane & 3;
    int n = blockIdx.x * 4 + wid;
    int c0 = j * 8;
    int beg = row_ptr[n], end = row_ptr[n + 1];

    float4 at0 = *(const float4*)(att + c0);
    float4 at1 = *(const float4*)(att + c0 + 4);
    float4 xr0 = *(const float4*)(xr + n * 32 + c0);
    float4 xr1 = *(const float4*)(xr + n * 32 + c0 + 4);

    float m = -INFINITY, den = 0.0f, acc[8] = {0, 0, 0, 0, 0, 0, 0, 0};
    for (int p = beg + g; p < end; p += 16) {
        int s = csr_src[p];
        const float4* rp = (const float4*)(xl + s * 32 + c0);
        float4 v0 = rp[0], v1 = rp[1];
        float e = edge_score(v0, v1, xr0, xr1, at0, at1);
        online_update(e, m, den, acc, v0, v1);
    }
    float o[8];
    merge_groups(m, den, acc, beg < end, o);

    if (g == 0) {
        float4 bc0 = *(const float4*)(bconv + c0);
        float4 bc1 = *(const float4*)(bconv + c0 + 4);
        float r[8] = {o[0] + bc0.x, o[1] + bc0.y, o[2] + bc0.z, o[3] + bc0.w,
                      o[4] + bc1.x, o[5] + bc1.y, o[6] + bc1.z, o[7] + bc1.w};
#pragma unroll
        for (int i = 0; i < 8; ++i) r[i] = tanhf(r[i]);
        float4* op = (float4*)(out + n * 32 + c0);
        op[0] = make_float4(r[0], r[1], r[2], r[3]);
        op[1] = make_float4(r[4], r[5], r[6], r[7]);
    }
}

// ---------------- conv3 + y2/x2/out fused ----------------------------------
// s = relu(conv3 + bconv3) kept in-wave; y2 = [s|hidden]@W2.T + b2

__global__ __launch_bounds__(256) void conv3_out_kernel(const int* __restrict__ row_ptr,
                                                        const int* __restrict__ csr_src,
                                                        const float* __restrict__ xl,
                                                        const float* __restrict__ xr,
                                                        const float* __restrict__ att,
                                                        const float* __restrict__ bconv,
                                                        const float* __restrict__ hidden,
                                                        const float* __restrict__ W2,
                                                        const float* __restrict__ b2,
                                                        const float* __restrict__ x_t,
                                                        const float* __restrict__ mask,
                                                        float* __restrict__ x2,
                                                        float* __restrict__ out_t) {
    __shared__ float W2s[64 * 16];   // transposed [c][f] -> conflict-free reads
    for (int idx = threadIdx.x; idx < 64 * 16; idx += 256) {
        int f = idx & 15, c = idx >> 4;
        W2s[c * 16 + f] = W2[f * 64 + c];
    }
    __syncthreads();

    int wid  = threadIdx.x >> 6;
    int lane = threadIdx.x & 63;
    int g = lane >> 2, j = lane & 3;
    int n = blockIdx.x * 4 + wid;
    int c0 = j * 8;
    int beg = row_ptr[n], end = row_ptr[n + 1];

    float4 at0 = *(const float4*)(att + c0);
    float4 at1 = *(const float4*)(att + c0 + 4);
    float4 xr0 = *(const float4*)(xr + n * 32 + c0);
    float4 xr1 = *(const float4*)(xr + n * 32 + c0 + 4);

    float m = -INFINITY, den = 0.0f, acc[8] = {0, 0, 0, 0, 0, 0, 0, 0};
    for (int p = beg + g; p < end; p += 16) {
        int s = csr_src[p];
        const float4* rp = (const float4*)(xl + s * 32 + c0);
        float4 v0 = rp[0], v1 = rp[1];
        float e = edge_score(v0, v1, xr0, xr1, at0, at1);
        online_update(e, m, den, acc, v0, v1);
    }
    float o[8];
    merge_groups(m, den, acc, beg < end, o);

    // s (relu) in all lanes, j-sliced
    float4 bc0 = *(const float4*)(bconv + c0);
    float4 bc1 = *(const float4*)(bconv + c0 + 4);
    float r[8] = {fmaxf(o[0] + bc0.x, 0.f), fmaxf(o[1] + bc0.y, 0.f),
                  fmaxf(o[2] + bc0.z, 0.f), fmaxf(o[3] + bc0.w, 0.f),
                  fmaxf(o[4] + bc1.x, 0.f), fmaxf(o[5] + bc1.y, 0.f),
                  fmaxf(o[6] + bc1.z, 0.f), fmaxf(o[7] + bc1.w, 0.f)};
    // hidden slice
    float4 h0 = *(const float4*)(hidden + n * 32 + c0);
    float4 h1 = *(const float4*)(hidden + n * 32 + c0 + 4);
    float hv[8] = {h0.x, h0.y, h0.z, h0.w, h1.x, h1.y, h1.z, h1.w};

    int f = lane & 15;
    int base = lane & ~3;
    float y = b2[f];
#pragma unroll
    for (int j2 = 0; j2 < 4; ++j2) {
#pragma unroll
        for (int i = 0; i < 8; ++i) {
            float sv = __shfl(r[i], base + j2);
            float hh = __shfl(hv[i], base + j2);
            int c = j2 * 8 + i;
            y += sv * W2s[c * 16 + f] + hh * W2s[(32 + c) * 16 + f];
        }
    }
    if (lane < 16) {
        float mv = mask[n];
        float xv = x_t[n * 16 + f];
        float rr = (mv > 0.5f) ? xv : y;
        x2[n * 16 + f] = rr;
        out_t[n * 16 + f] = rr;
    }
}

// ---------------- hidden update + y1/x1 + dense for gate 3 ----------------
// ft2 = [x1(0..15), mask(16), hidden(17..48), labels(49..52)]

__global__ __launch_bounds__(256) void update_dense3_kernel(
        const float* __restrict__ g_update, const float* __restrict__ g_cell,
        float* __restrict__ hidden,
        const float* __restrict__ x_t, const float* __restrict__ mask,
        const float* __restrict__ labels,
        const float* __restrict__ W1, const float* __restrict__ b1,
        const float* __restrict__ Wl3, const float* __restrict__ bl3,
        const float* __restrict__ Wr3, const float* __restrict__ br3,
        float* __restrict__ xl, float* __restrict__ xr) {
    __shared__ float Wl_s[WD];
    __shared__ float Wr_s[WD];
    __shared__ float W1_s[FEAT * HID];
    __shared__ float inp_s[8][DIN];
    __shared__ float hs[8][HID + 1];
    for (int idx = threadIdx.x; idx < WD; idx += 256) {
        Wl_s[idx] = Wl3[idx];
        Wr_s[idx] = Wr3[idx];
    }
    for (int idx = threadIdx.x; idx < FEAT * HID; idx += 256) W1_s[idx] = W1[idx];
    int ni = threadIdx.x >> 5, k = threadIdx.x & 31;
    int node = blockIdx.x * 8 + ni;
    float u = g_update[node * 32 + k];
    float c = g_cell[node * 32 + k];
    float h = hidden[node * 32 + k];
    float hn = u * h + (1.0f - u) * c;
    hidden[node * 32 + k] = hn;
    hs[ni][k] = hn;
    inp_s[ni][17 + k] = hn;
    if (k == 0) inp_s[ni][16] = mask[node];
    if (k < 4)  inp_s[ni][49 + k] = labels[node * 4 + k];
    __syncthreads();
    if (k < 16) {
        float a = b1[k];
        const float* w = &W1_s[k * 32];
#pragma unroll
        for (int i = 0; i < 32; ++i) a += hs[ni][i] * w[i];
        float mv = mask[node];
        inp_s[ni][k] = (mv > 0.5f) ? x_t[node * 16 + k] : a;
    }
    __syncthreads();
    float al = bl3[k], ar = br3[k];
    const float* wl = &Wl_s[k * DIN];
    const float* wr = &Wr_s[k * DIN];
#pragma unroll
    for (int i = 0; i < DIN; ++i) {
        float xv = inp_s[ni][i];
        al += xv * wl[i];
        ar += xv * wr[i];
    }
    xl[node * 32 + k] = al;
    xr[node * 32 + k] = ar;
}

// ---------------- launch ----------------

extern "C" void kernel_launch(void* const* d_in, const int* in_sizes, int n_in,
                              void* d_out, int out_size, void* d_ws, size_t ws_size,
                              hipStream_t stream) {
    const float* x      = (const float*)d_in[0];
    const float* mask   = (const float*)d_in[1];
    const float* labels = (const float*)d_in[2];
    const int*   src    = (const int*)d_in[3];
    const int*   dst    = src + EE;
    // d_in[4] = edge_weight: unused by the reference
    const float* Wl    = (const float*)d_in[5];
    const float* bl    = (const float*)d_in[6];
    const float* Wr    = (const float*)d_in[7];
    const float* br    = (const float*)d_in[8];
    const float* att   = (const float*)d_in[9];
    const float* bconv = (const float*)d_in[10];
    const float* W1    = (const float*)d_in[11];
    const float* b1    = (const float*)d_in[12];
    const float* W2    = (const float*)d_in[13];
    const float* b2    = (const float*)d_in[14];
    float* out = (float*)d_out;

    char* ws = (char*)d_ws;
    size_t off = 0;
    auto alloc = [&](size_t bytes) -> void* {
        void* p = ws + off;
        off = (off + bytes + 255) & ~(size_t)255;
        return p;
    };
    int*   row_ptr = (int*)alloc((NN + 1) * sizeof(int));
    int*   deg     = (int*)alloc(NN * sizeof(int));
    int*   csr_src = (int*)alloc(EE * sizeof(int));
    float* hidden  = (float*)alloc(NN * HID * sizeof(float));
    float* x2      = (float*)alloc(NN * FEAT * sizeof(float));
    float* xl01    = (float*)alloc(NN * 64 * sizeof(float));
    float* xr01    = (float*)alloc(NN * 64 * sizeof(float));
    float* xl      = (float*)alloc(NN * HID * sizeof(float));
    float* xr      = (float*)alloc(NN * HID * sizeof(float));
    float* g0      = (float*)alloc(NN * HID * sizeof(float));  // reset
    float* g1      = (float*)alloc(NN * HID * sizeof(float));  // update
    float* g2      = (float*)alloc(NN * HID * sizeof(float));  // cell

    // CSR build (dst is identical for every conv, build once per call)
    zero_i32<<<(NN + 255) / 256, 256, 0, stream>>>(deg, NN);
    hist_kernel<<<EE / 256, 256, 0, stream>>>(dst, deg);
    scan_kernel<<<1, 1024, 0, stream>>>(deg, row_ptr);
    zero_i32<<<(NN + 255) / 256, 256, 0, stream>>>(deg, NN);
    scatter_kernel<<<EE / 256, 256, 0, stream>>>(src, dst, row_ptr, deg, csr_src);
    init_kernel<<<NN * HID / 256, 256, 0, stream>>>(x, mask, hidden, x2);

    for (int t = 0; t < TT; ++t) {
        const float* xt = x + (size_t)t * NN * FEAT;
        float* out_t = out + (size_t)t * NN * FEAT;
        // gates 0+1 dense (shared input), interleaved output
        dense01_kernel<<<NN / 8, 256, 0, stream>>>(x2, mask, labels, hidden,
            Wl, bl, Wr, br, xl01, xr01);
        // gates 0+1 conv in one CSR walk -> reset (g0), update (g1)
        conv01_kernel<<<NN / 4, 256, 0, stream>>>(row_ptr, csr_src, xl01, xr01,
            att, bconv, g0, g1);
        // gate 2 dense: cin's h-part = reset*hidden
        dense_kernel<<<NN / 8, 256, 0, stream>>>(x2, mask, labels, hidden, g0,
            Wl + 2 * WD, bl + 2 * HID, Wr + 2 * WD, br + 2 * HID, xl, xr);
        conv2_kernel<<<NN / 4, 256, 0, stream>>>(row_ptr, csr_src, xl, xr,
            att + 2 * HID, bconv + 2 * HID, g2);
        // hidden = u*h+(1-u)*c; y1; x1; dense for gate 3 (node-local, fused)
        update_dense3_kernel<<<NN / 8, 256, 0, stream>>>(g1, g2, hidden, xt, mask, labels,
            W1, b1, Wl + 3 * WD, bl + 3 * HID, Wr + 3 * WD, br + 3 * HID, xl, xr);
        // gate 3 conv + y2/x2/out fused (s never materialized)
        conv3_out_kernel<<<NN / 4, 256, 0, stream>>>(row_ptr, csr_src, xl, xr,
            att + 3 * HID, bconv + 3 * HID, hidden, W2, b2, xt, mask, x2, out_t);
    }
}